// Round 1
// baseline (345.110 us; speedup 1.0000x reference)
//
#include <hip/hip_runtime.h>
#include <hip/hip_bf16.h>

#define D 1024
#define SLEN 2048
#define BS 16
#define MROWS (BS*SLEN)   // 32768

typedef __attribute__((ext_vector_type(8))) short short8;
typedef __attribute__((ext_vector_type(4))) float f32x4;

__device__ __forceinline__ short f2bf(float f) {
  __hip_bfloat16 h = __float2bfloat16(f);
  return __builtin_bit_cast(short, h);
}

#define GLOBAL_LOAD_LDS16(lds, g) \
  __builtin_amdgcn_global_load_lds((const __attribute__((address_space(1))) void*)(g), \
                                   (__attribute__((address_space(3))) void*)(lds), 16, 0, 0)

// ---------------- Kernel 1: Wk (v,d) fp32 -> WkT (d,v) bf16 ----------------
__global__ __launch_bounds__(256) void wk_transpose(const float* __restrict__ Wk,
                                                    short* __restrict__ WkT) {
  __shared__ float tile[64][65];
  const int bv = blockIdx.x, bd = blockIdx.y, t = threadIdx.x;
#pragma unroll
  for (int it = 0; it < 16; ++it) {
    int idx = it*256 + t;
    int r = idx >> 6, c = idx & 63;
    tile[r][c] = Wk[(size_t)(bv*64 + r)*D + bd*64 + c];
  }
  __syncthreads();
#pragma unroll
  for (int it = 0; it < 16; ++it) {
    int idx = it*256 + t;
    int r = idx >> 6, c = idx & 63;
    WkT[(size_t)(bd*64 + r)*D + bv*64 + c] = f2bf(tile[c][r]);
  }
}

// ---------------- Kernel 2: e[b,s] = sum_d tanh(relu(states@Wk + bk))*We_k --
// 512 blocks, 512 threads (8 waves). Block = 64 M-rows x full N=1024.
// K streamed in 32-chunks, double-buffered. Wave tile 64x128 (4x8 MFMA 16x16x32).
__global__ __launch_bounds__(512, 2) void energy_gemm(
    const float* __restrict__ states, const short* __restrict__ WkT,
    const float* __restrict__ bk, const float* __restrict__ We,
    float* __restrict__ eout)
{
  __shared__ short Abuf[2][64*32];     // 4 KB each
  __shared__ short Bbuf[2][1024*32];   // 64 KB each -> 136 KB total

  const int tid  = threadIdx.x;
  const int w    = tid >> 6;        // wave 0..7
  const int lane = tid & 63;
  const int quad = lane >> 4;       // 0..3
  const int l16  = lane & 15;

  f32x4 acc[4][8];
#pragma unroll
  for (int mi = 0; mi < 4; ++mi)
#pragma unroll
    for (int ni = 0; ni < 8; ++ni)
      acc[mi][ni] = (f32x4){0.f, 0.f, 0.f, 0.f};

  const int arow = tid >> 3;            // 0..63
  const int acol = (tid & 7) * 4;       // 0..28
  const float* Ag = states + ((size_t)blockIdx.x*64 + arow)*D + acol;
  const int brow_lane = lane >> 2;      // 0..15
  const int bcol_lane = (lane & 3) * 8; // 0,8,16,24

  // prologue: stage chunk 0 -> buffer 0
  {
    float4 a4 = *(const float4*)(Ag);
#pragma unroll
    for (int j2 = 0; j2 < 8; ++j2) {
      int j = w*8 + j2;   // 16 rows per issue
      const short* g = WkT + (size_t)(j*16 + brow_lane)*D + bcol_lane;
      GLOBAL_LOAD_LDS16(&Bbuf[0][j*512], g);
    }
    short4 p; p.x = f2bf(a4.x); p.y = f2bf(a4.y); p.z = f2bf(a4.z); p.w = f2bf(a4.w);
    *(short4*)(&Abuf[0][arow*32 + acol]) = p;
  }
  __syncthreads();

  for (int i = 0; i < 32; ++i) {
    const int cb = i & 1, nb = cb ^ 1;
    float4 a4;
    if (i < 31) {
      const int k0 = (i+1)*32;
      a4 = *(const float4*)(Ag + k0);
#pragma unroll
      for (int j2 = 0; j2 < 8; ++j2) {
        int j = w*8 + j2;
        const short* g = WkT + (size_t)(j*16 + brow_lane)*D + k0 + bcol_lane;
        GLOBAL_LOAD_LDS16(&Bbuf[nb][j*512], g);
      }
    }

    // compute on current buffer
    short8 fa[4], fb[8];
    const short* Ab = &Abuf[cb][0];
    const short* Bb = &Bbuf[cb][0];
#pragma unroll
    for (int mi = 0; mi < 4; ++mi)
      fa[mi] = *(const short8*)(Ab + (mi*16 + l16)*32 + quad*8);
#pragma unroll
    for (int ni = 0; ni < 8; ++ni)
      fb[ni] = *(const short8*)(Bb + (w*128 + ni*16 + l16)*32 + quad*8);
#pragma unroll
    for (int mi = 0; mi < 4; ++mi)
#pragma unroll
      for (int ni = 0; ni < 8; ++ni)
        acc[mi][ni] = __builtin_amdgcn_mfma_f32_16x16x32_bf16(fa[mi], fb[ni], acc[mi][ni], 0, 0, 0);

    if (i < 31) {  // convert+write A AFTER compute so the global load overlaps MFMA
      short4 p; p.x = f2bf(a4.x); p.y = f2bf(a4.y); p.z = f2bf(a4.z); p.w = f2bf(a4.w);
      *(short4*)(&Abuf[nb][arow*32 + acol]) = p;
    }
    __syncthreads();
  }

  // epilogue: f = tanh(relu(c + bk[col])) * We_k[col], reduce over cols
  float esum[16];
#pragma unroll
  for (int q = 0; q < 16; ++q) esum[q] = 0.f;
#pragma unroll
  for (int ni = 0; ni < 8; ++ni) {
    const int col = w*128 + ni*16 + l16;
    const float bkv = bk[col];
    const float wev = We[D + col];   // We_k = We[1024:2048]
#pragma unroll
    for (int mi = 0; mi < 4; ++mi)
#pragma unroll
      for (int r = 0; r < 4; ++r) {
        float x = acc[mi][ni][r] + bkv;
        x = fmaxf(x, 0.f);
        float ex = __expf(2.f * x);
        float th = 1.f - 2.f/(ex + 1.f);
        esum[mi*4 + r] += th * wev;
      }
  }
  // reduce across the 16 lanes of each quad (cols)
#pragma unroll
  for (int d = 1; d < 16; d <<= 1)
#pragma unroll
    for (int q = 0; q < 16; ++q)
      esum[q] += __shfl_xor(esum[q], d, 64);

  // cross-wave reduce via LDS (reuse Bbuf after final barrier)
  float* red = (float*)&Bbuf[0][0];   // [64 rows][8 waves]
  if (l16 == 0) {
#pragma unroll
    for (int mi = 0; mi < 4; ++mi)
#pragma unroll
      for (int r = 0; r < 4; ++r)
        red[(mi*16 + quad*4 + r)*8 + w] = esum[mi*4 + r];
  }
  __syncthreads();
  if (tid < 64) {
    float s = 0.f;
#pragma unroll
    for (int wi = 0; wi < 8; ++wi) s += red[tid*8 + wi];
    eout[(size_t)blockIdx.x*64 + tid] = s;
  }
}

// ---------------- Kernel 3: in-place row softmax over s=2048 ----------------
__global__ __launch_bounds__(256) void softmax_rows(float* __restrict__ e) {
  const int b = blockIdx.x, t = threadIdx.x;
  __shared__ float red[256];
  float v[8];
  float m = -1e30f;
#pragma unroll
  for (int j = 0; j < 8; ++j) {
    v[j] = e[(size_t)b*SLEN + j*256 + t];
    m = fmaxf(m, v[j]);
  }
  red[t] = m; __syncthreads();
  for (int s = 128; s > 0; s >>= 1) {
    if (t < s) red[t] = fmaxf(red[t], red[t+s]);
    __syncthreads();
  }
  m = red[0];
  __syncthreads();
  float sum = 0.f;
#pragma unroll
  for (int j = 0; j < 8; ++j) { v[j] = __expf(v[j] - m); sum += v[j]; }
  red[t] = sum; __syncthreads();
  for (int s = 128; s > 0; s >>= 1) {
    if (t < s) red[t] += red[t+s];
    __syncthreads();
  }
  const float inv = 1.f / red[0];
#pragma unroll
  for (int j = 0; j < 8; ++j)
    e[(size_t)b*SLEN + j*256 + t] = v[j] * inv;
}

// ---------------- Kernel 4: attn[b,d] = sum_s w[b,s]*states[b,s,d] ----------
__global__ __launch_bounds__(256) void attn_reduce(
    const float* __restrict__ states, const float* __restrict__ wts,
    float* __restrict__ attn)
{
  const int dc = blockIdx.x;   // 0..3
  const int sc = blockIdx.y;   // 0..15 (128 s each)
  const int b  = blockIdx.z;   // 0..15
  const int t  = threadIdx.x;
  __shared__ float wsh[128];
  if (t < 128) wsh[t] = wts[(size_t)b*SLEN + sc*128 + t];
  __syncthreads();
  const float* sp = states + ((size_t)b*SLEN + sc*128)*D + dc*256 + t;
  float acc = 0.f;
#pragma unroll 8
  for (int s = 0; s < 128; ++s)
    acc = fmaf(wsh[s], sp[(size_t)s*D], acc);
  atomicAdd(attn + (size_t)b*D + dc*256 + t, acc);
}

extern "C" void kernel_launch(void* const* d_in, const int* in_sizes, int n_in,
                              void* d_out, int out_size, void* d_ws, size_t ws_size,
                              hipStream_t stream) {
  // inputs: 0=query 1=states 2=Wq 3=bq 4=Wk 5=bk 6=We 7=be
  // q-path (0,2,3), We_q and be are per-row-constant in energy -> cancel in softmax.
  const float* states = (const float*)d_in[1];
  const float* Wk     = (const float*)d_in[4];
  const float* bk     = (const float*)d_in[5];
  const float* We     = (const float*)d_in[6];
  float* out = (float*)d_out;            // [0:32768) attn_weights, [32768:49152) attn
  short* WkT = (short*)d_ws;             // 2 MB bf16 scratch

  (void)in_sizes; (void)n_in; (void)out_size; (void)ws_size;

  hipMemsetAsync(out + MROWS, 0, (size_t)BS*D*sizeof(float), stream);
  wk_transpose<<<dim3(16,16), 256, 0, stream>>>(Wk, WkT);
  energy_gemm<<<MROWS/64, 512, 0, stream>>>(states, WkT, bk, We, out);
  softmax_rows<<<BS, 256, 0, stream>>>(out);
  attn_reduce<<<dim3(4,16,16), 256, 0, stream>>>(states, out, out + MROWS);
}